// Round 8
// baseline (382.091 us; speedup 1.0000x reference)
//
#include <hip/hip_runtime.h>
#include <math.h>

#ifndef M_PI
#define M_PI 3.14159265358979323846
#endif

// ---------------- workspace layout (float offsets) ----------------
// double tables (k0a): [0..353] doubles at float offset 0 (708 floats, pad 720)
#define OFF_TRIG 708              // float2 cs32[32] then cs64[64]  (192 floats)
#define OFF_D1F 900               // [16][64][31]                 31744
#define OFF_D1I 32644             // D1IT: [j=32][mh=31][l=16][nh=32]  507904
#define OFF_D2F 540548            // D2FT: [j=32][pq=225][l=8]    57600
#define OFF_S2  598148            // [8][15][15]                   1800
#define OFF_XH  599948            // float2 [16][16*31]           15872 floats
#define OFF_XMN 615820            // float2 [16][32][32][225]   7372800 floats
#define OFF_U   7988620           // float2 [16*32][8][225]     1843200 floats
#define OFF_PART 9831820          // [16][64][32]                 32768 floats

static __device__ __forceinline__ int iabs_(int v) { return v < 0 ? -v : v; }

static __device__ __forceinline__ double powi_d(double x, int e) {
    double r = 1.0;
    while (e) { if (e & 1) r *= x; x *= x; e >>= 1; }
    return r;
}

// ---------------- K0a: tiny table precompute (1 block) ----------------
__global__ __launch_bounds__(256) void k0a_tables(float* __restrict__ ws) {
    double* T = (double*)ws;
    int t = threadIdx.x;
    __shared__ double lg[64];
    if (t < 64) lg[t] = (t == 0) ? 0.0 : log((double)t);
    __syncthreads();
    if (t == 0) {
        double s = 0.0;
        for (int i = 0; i < 64; ++i) { s += lg[i]; T[i] = s; }   // LF[i]=log(i!)
    }
    if (t < 64) {
        double beta = M_PI * (2.0 * t + 1.0) / 128.0;
        double s = 0.0;
        for (int k = 0; k < 32; ++k) s += sin((2.0 * k + 1.0) * beta) / (2.0 * k + 1.0);
        T[64 + t] = 2.0 / 32.0 * sin(beta) * s;
        T[160 + t] = cos(0.5 * beta);
        T[224 + t] = sin(0.5 * beta);
    }
    if (t >= 64 && t < 96) {
        int j = t - 64;
        double beta = M_PI * (2.0 * j + 1.0) / 64.0;
        double s = 0.0;
        for (int k = 0; k < 16; ++k) s += sin((2.0 * k + 1.0) * beta) / (2.0 * k + 1.0);
        T[128 + j] = 2.0 / 16.0 * sin(beta) * s;
        T[288 + j] = cos(0.5 * beta);
        T[320 + j] = sin(0.5 * beta);
    }
    if (t == 96) {
        T[352] = cos(M_PI / 64.0);
        T[353] = sin(M_PI / 64.0);
    }
    float2* F = (float2*)(ws + OFF_TRIG);
    if (t < 32) {
        double a = 2.0 * M_PI * (double)t / 32.0;
        F[t] = make_float2((float)cos(a), (float)sin(a));
    }
    if (t >= 128 && t < 192) {
        int i = t - 128;
        double a = 2.0 * M_PI * (double)i / 64.0;
        F[32 + i] = make_float2((float)cos(a), (float)sin(a));
    }
}

// ---------------- K0: build Wigner constant tables ----------------
__device__ double wig_fast(int l, int m, int n, double cb, double sb, const double* LF) {
    int kmin = max(0, m - n), kmax = min(l + m, l - n);
    if (kmax < kmin) return 0.0;
    double lc = 0.5 * (LF[l + m] + LF[l - m] + LF[l + n] + LF[l - n])
              - LF[kmin] - LF[l + m - kmin] - LF[l - n - kmin] - LF[n - m + kmin];
    double t = exp(lc) * powi_d(cb, 2 * l + m - n - 2 * kmin)
                       * powi_d(sb, n - m + 2 * kmin);
    if (kmin & 1) t = -t;
    double ratio = (sb * sb) / (cb * cb);
    double s = t;
    for (int k = kmin; k < kmax; ++k) {
        t *= -(((double)(l + m - k) * (double)(l - n - k)) /
               ((double)(k + 1) * (double)(n - m + k + 1))) * ratio;
        s += t;
    }
    return s;
}

__global__ __launch_bounds__(256) void k0_consts(float* __restrict__ ws) {
    const double* T = (const double*)ws;
    __shared__ double LF[64];
    int tid = threadIdx.x;
    if (tid < 64) LF[tid] = T[tid];
    __syncthreads();
    int gid = blockIdx.x * 256 + tid;
    if (gid >= 599048) return;

    if (gid < 31744) {                       // D1F [l][j][mh]
        int mh = gid % 31, j = (gid / 31) % 64, l = gid / (31 * 64);
        int m = mh - 15;
        double v = 0.0;
        if (iabs_(m) <= l)
            v = T[64 + j] * wig_fast(l, m, 0, T[160 + j], T[224 + j], LF);
        ws[OFF_D1F + gid] = (float)v;
    } else if (gid < 539648) {               // D1IT [j][mh][l][nh32]
        int r = gid - 31744;
        int nh = r & 31;
        int l  = (r >> 5) & 15;
        int mh = (r >> 9) % 31;
        int j  = r / (512 * 31);
        int m = mh - 15, n = nh - 15;
        double v = 0.0;
        if (nh < 31 && iabs_(m) <= l && iabs_(n) <= l)
            v = (2.0 * l + 1.0) * wig_fast(l, m, n, T[288 + j], T[320 + j], LF);
        ws[OFF_D1I + r] = (float)v;
    } else if (gid < 597248) {               // D2FT [j][pq][l]
        int r = gid - 539648;
        int l = r & 7;
        int pq = (r >> 3) % 225;
        int j = r / 1800;
        int mh = pq / 15, nh = pq % 15;
        int m = mh - 7, n = nh - 7;
        double v = 0.0;
        if (iabs_(m) <= l && iabs_(n) <= l)
            v = T[128 + j] * wig_fast(l, m, n, T[288 + j], T[320 + j], LF);
        ws[OFF_D2F + r] = (float)v;
    } else {                                 // S2 = D2I[:,0,:,:]
        int r = gid - 597248;
        int nh = r % 15, mh = (r / 15) % 15, l = r / 225;
        int m = mh - 7, n = nh - 7;
        double v = 0.0;
        if (iabs_(m) <= l && iabs_(n) <= l)
            v = (2.0 * l + 1.0) * wig_fast(l, m, n, T[352], T[353], LF);
        ws[OFF_S2 + r] = (float)v;
    }
}

// ---------------- K1: x -> xm -> xh ----------------
__global__ __launch_bounds__(256) void k1_xh(const float* __restrict__ x,
                                             const float* __restrict__ ws,
                                             float2* __restrict__ xh) {
    __shared__ float  xs[64 * 64];
    __shared__ float2 xm[64 * 8];
    __shared__ float2 cs64[64];
    int c = blockIdx.x, b = blockIdx.y, tid = threadIdx.x;
    int mh0 = c * 8;
    int cnt = min(8, 31 - mh0);
    for (int i = tid; i < 4096; i += 256) xs[i] = x[b * 4096 + i];
    if (tid < 64) cs64[tid] = ((const float2*)(ws + OFF_TRIG))[32 + tid];
    __syncthreads();
    for (int i = tid; i < 512; i += 256) {
        int j = i >> 3, mi = i & 7;
        if (mi < cnt) {
            int mu = mh0 + mi - 15;
            float re = 0.f, im = 0.f;
            for (int t = 0; t < 64; ++t) {
                float2 w = cs64[(mu * t) & 63];
                float xv = xs[j * 64 + t];
                re += xv * w.x;
                im -= xv * w.y;
            }
            xm[i] = make_float2(re, im);
        }
    }
    __syncthreads();
    const float* D1F = ws + OFF_D1F;
    if (tid < 128) {
        int l = tid >> 3, mi = tid & 7;
        if (mi < cnt) {
            int mh = mh0 + mi;
            float re = 0.f, im = 0.f;
            for (int j = 0; j < 64; ++j) {
                float d = D1F[(l * 64 + j) * 31 + mh];
                float2 v = xm[j * 8 + mi];
                re += d * v.x;
                im += d * v.y;
            }
            xh[b * 496 + l * 31 + mh] = make_float2(re, im);
        }
    }
}

// ------- K2: per-(b,f,j) plane; Hermitian-half iDFT2 + relu + fwd DFT2 -------
__global__ __launch_bounds__(256) void k2_planes(const float* __restrict__ w1r,
                                                 const float* __restrict__ w1i,
                                                 const float* __restrict__ ws,
                                                 float2* __restrict__ xmn) {
    __shared__ char ar[16896];
    __shared__ float2 cs[32];
    float2* As  = (float2*)ar;              // 496 f2 @0           (f1 phase)
    float2* Wc  = (float2*)(ar + 4096);     // 16x32 f2 @4096      (f1 phase)
    float2* f1  = (float2*)(ar + 8448);     // 31 rows stride34 f2 (dies after fH)
    float2* fH  = (float2*)ar;              // 16 rows stride34 f2 @0 [0,4352)
    float2* tls = (float2*)(ar + 4608);     // 17 rows stride33 f2 [4608,9096)
    float*  ssb = (float*)(ar + 9216);      // 32x33 f [9216,13440)
    float2* gg  = (float2*)ar;              // 32x15 f2 @0

    int j = blockIdx.x, f = blockIdx.y, b = blockIdx.z;
    int tid = threadIdx.x;
    const float2* xh = (const float2*)(ws + OFF_XH);

    if (tid < 32) cs[tid] = ((const float2*)(ws + OFF_TRIG))[tid];
    for (int i = tid; i < 496; i += 256) As[i] = xh[b * 496 + i];
    for (int i = tid; i < 512; i += 256) {
        int l = i >> 5, nh = i & 31;
        float mask = (nh < 31 && iabs_(nh - 15) <= l) ? 1.0f : 0.0f;
        int src = f * 496 + l * 31 + min(nh, 30);
        Wc[i] = make_float2(w1r[src] * mask, -w1i[src] * mask);
    }
    __syncthreads();
    // ---- f1[m, nh0..nh0+3] = sum_l D1IT[j,m,l,nh] * A[l,m] * W[l,nh] ----
    {
        int mrow = tid >> 3;
        int nh0 = (tid & 7) * 4;
        if (mrow < 31) {
            int l0 = iabs_(mrow - 15);
            float2 a0 = {0,0}, a1 = {0,0}, a2 = {0,0}, a3 = {0,0};
            const float* Dbase = ws + OFF_D1I + ((j * 31 + mrow) * 16) * 32 + nh0;
            for (int l = l0; l < 16; ++l) {
                float2 a = As[l * 31 + mrow];
                float4 w01 = *(const float4*)(Wc + l * 32 + nh0);
                float4 w23 = *(const float4*)(Wc + l * 32 + nh0 + 2);
                float4 d = *(const float4*)(Dbase + l * 32);
                float t;
                t = a.x*w01.x - a.y*w01.y; a0.x += d.x*t;
                t = a.x*w01.y + a.y*w01.x; a0.y += d.x*t;
                t = a.x*w01.z - a.y*w01.w; a1.x += d.y*t;
                t = a.x*w01.w + a.y*w01.z; a1.y += d.y*t;
                t = a.x*w23.x - a.y*w23.y; a2.x += d.z*t;
                t = a.x*w23.y + a.y*w23.x; a2.y += d.z*t;
                t = a.x*w23.z - a.y*w23.w; a3.x += d.w*t;
                t = a.x*w23.w + a.y*w23.z; a3.y += d.w*t;
            }
            float2* fr = f1 + mrow * 34 + nh0;
            fr[0] = a0; fr[1] = a1; fr[2] = a2; fr[3] = a3;
        }
    }
    __syncthreads();
    // ---- fH[mm,nh] = 0.5*(f1[mm+15,nh] + conj(f1[15-mm,30-nh])), mm=0..15 ----
    for (int i = tid; i < 512; i += 256) {
        int mm = i >> 5, nh = i & 31;
        float2 v = make_float2(0.f, 0.f);
        if (nh < 31) {
            float2 a = f1[(mm + 15) * 34 + nh];
            float2 bb = f1[(15 - mm) * 34 + (30 - nh)];
            v = make_float2(0.5f * (a.x + bb.x), 0.5f * (a.y - bb.y));
        }
        fH[mm * 34 + nh] = v;
    }
    __syncthreads();
    // ---- t[mm,v] = sum_n fH[mm,n] e^{+i n v th}, v = v0+8k (i^{nk} signs) ----
    if (tid < 128) {
        int mm = tid >> 3, v0 = tid & 7;
        const float2* frow = fH + mm * 34;
        float2 a0 = {0,0}, a1 = {0,0}, a2 = {0,0}, a3 = {0,0};
        for (int nb = 0; nb < 32; nb += 4) {
            float4 q01 = *(const float4*)(frow + nb);
            float4 q23 = *(const float4*)(frow + nb + 2);
            { // n mod 4 = 1
                float2 w = cs[((nb - 15) * v0) & 31];
                float px = q01.x*w.x - q01.y*w.y, py = q01.x*w.y + q01.y*w.x;
                a0.x += px; a0.y += py;  a1.x -= py; a1.y += px;
                a2.x -= px; a2.y -= py;  a3.x += py; a3.y -= px;
            }
            { // n mod 4 = 2
                float2 w = cs[((nb - 14) * v0) & 31];
                float px = q01.z*w.x - q01.w*w.y, py = q01.z*w.y + q01.w*w.x;
                a0.x += px; a0.y += py;  a1.x -= px; a1.y -= py;
                a2.x += px; a2.y += py;  a3.x -= px; a3.y -= py;
            }
            { // n mod 4 = 3
                float2 w = cs[((nb - 13) * v0) & 31];
                float px = q23.x*w.x - q23.y*w.y, py = q23.x*w.y + q23.y*w.x;
                a0.x += px; a0.y += py;  a1.x += py; a1.y -= px;
                a2.x -= px; a2.y -= py;  a3.x -= py; a3.y += px;
            }
            { // n mod 4 = 0
                float2 w = cs[((nb - 12) * v0) & 31];
                float px = q23.z*w.x - q23.w*w.y, py = q23.z*w.y + q23.w*w.x;
                a0.x += px; a0.y += py;  a1.x += px; a1.y += py;
                a2.x += px; a2.y += py;  a3.x += px; a3.y += py;
            }
        }
        float2* trow = tls + mm * 33;
        trow[v0] = a0; trow[v0 + 8] = a1; trow[v0 + 16] = a2; trow[v0 + 24] = a3;
    } else if (tid < 161) {
        tls[16 * 33 + (tid - 128)] = make_float2(0.f, 0.f);
    }
    __syncthreads();
    // ---- ss[u,v] = relu( t0.re + 2 sum_{m=1..15} Re(t[m,v] e^{imu th}) ) ----
    {
        int v = tid & 31, u0 = tid >> 5;
        float s0 = 0, s1 = 0, s2 = 0, s3 = 0;
        for (int mb = 0; mb < 4; ++mb) {
            int r1 = mb * 4 + 1;
            {
                float2 tv = tls[r1 * 33 + v];       float2 w = cs[(r1 * u0) & 31];
                float qx = tv.x*w.x - tv.y*w.y, qy = tv.x*w.y + tv.y*w.x;
                s0 += qx; s1 -= qy; s2 -= qx; s3 += qy;
            }
            {
                float2 tv = tls[(r1 + 1) * 33 + v]; float2 w = cs[((r1 + 1) * u0) & 31];
                float qx = tv.x*w.x - tv.y*w.y;
                s0 += qx; s1 -= qx; s2 += qx; s3 -= qx;
            }
            {
                float2 tv = tls[(r1 + 2) * 33 + v]; float2 w = cs[((r1 + 2) * u0) & 31];
                float qx = tv.x*w.x - tv.y*w.y, qy = tv.x*w.y + tv.y*w.x;
                s0 += qx; s1 += qy; s2 -= qx; s3 -= qy;
            }
            {
                float2 tv = tls[(r1 + 3) * 33 + v]; float2 w = cs[((r1 + 3) * u0) & 31];
                float qx = tv.x*w.x - tv.y*w.y;
                s0 += qx; s1 += qx; s2 += qx; s3 += qx;
            }
        }
        float t0x = tls[v].x;
        ssb[u0 * 33 + v]        = fmaxf(t0x + 2.f * s0, 0.f);
        ssb[(u0 + 8) * 33 + v]  = fmaxf(t0x + 2.f * s1, 0.f);
        ssb[(u0 + 16) * 33 + v] = fmaxf(t0x + 2.f * s2, 0.f);
        ssb[(u0 + 24) * 33 + v] = fmaxf(t0x + 2.f * s3, 0.f);
    }
    __syncthreads();
    // ---- gg[u,q'] = sum_v ss[u,v] e^{-i q' v th}, radix-4 over v ----
    {
        int u = tid >> 3, q = tid & 7;
        int qm = q & 3;
        float r1 = (qm == 0) ? 1.f : (qm == 2 ? -1.f : 0.f);
        float r2 = (qm & 1) ? -1.f : 1.f;
        float i1 = (qm == 1) ? -1.f : (qm == 3 ? 1.f : 0.f);
        float gx = 0.f, gy = 0.f;
        const float* srow = ssb + u * 33;
        for (int vb = 0; vb < 8; ++vb) {
            float s0 = srow[vb], s1 = srow[vb + 8], s2 = srow[vb + 16], s3 = srow[vb + 24];
            float zre = s0 + r1 * s1 + r2 * s2 + r1 * s3;
            float zim = i1 * (s1 - s3);
            float2 w = cs[(q * vb) & 31];
            gx += zre * w.x + zim * w.y;
            gy += zim * w.x - zre * w.y;
        }
        gg[u * 15 + 7 + q] = make_float2(gx, gy);
        if (q) gg[u * 15 + 7 - q] = make_float2(gx, -gy);
    }
    __syncthreads();
    // ---- h[p',q'] = sum_u gg[u,q'] e^{-i p' u th}, radix-4 over u ((-i)^{pk}) ----
    if (tid < 113) {
        int ph, qh;
        if (tid < 105) { ph = 8 + tid / 15; qh = tid % 15; }
        else           { ph = 7; qh = 7 + (tid - 105); }
        int p = ph - 7;
        int pm = p & 3;                       // p mod 4 (two's-complement & works)
        float hx = 0.f, hy = 0.f;
        if ((pm & 1) == 0) {                  // even p: z = (g0+g2) + e*(g1+g3)
            float e = (pm == 0) ? 1.f : -1.f;
            for (int u0 = 0; u0 < 8; ++u0) {
                float2 g0 = gg[u0 * 15 + qh],      g1 = gg[(u0 + 8) * 15 + qh];
                float2 g2 = gg[(u0 + 16) * 15 + qh], g3 = gg[(u0 + 24) * 15 + qh];
                float zre = (g0.x + g2.x) + e * (g1.x + g3.x);
                float zim = (g0.y + g2.y) + e * (g1.y + g3.y);
                float2 w = cs[(-(p * u0)) & 31];
                hx += zre * w.x - zim * w.y;
                hy += zre * w.y + zim * w.x;
            }
        } else {                              // odd p: z = (g0-g2) -+ i(g1-g3)
            float s = (pm == 1) ? 1.f : -1.f;
            for (int u0 = 0; u0 < 8; ++u0) {
                float2 g0 = gg[u0 * 15 + qh],      g1 = gg[(u0 + 8) * 15 + qh];
                float2 g2 = gg[(u0 + 16) * 15 + qh], g3 = gg[(u0 + 24) * 15 + qh];
                float dx = g1.x - g3.x, dy = g1.y - g3.y;
                float zre = (g0.x - g2.x) + s * dy;
                float zim = (g0.y - g2.y) - s * dx;
                float2 w = cs[(-(p * u0)) & 31];
                hx += zre * w.x - zim * w.y;
                hy += zre * w.y + zim * w.x;
            }
        }
        float2* outp = xmn + ((size_t)((b * 32 + f) * 32 + j)) * 225;
        outp[ph * 15 + qh] = make_float2(hx, hy);
        if (ph > 7 || qh > 7)
            outp[(14 - ph) * 15 + (14 - qh)] = make_float2(hx, -hy);
    }
}

// ---------- K34: fused xh2 + U, block per (b,c) ----------
__global__ __launch_bounds__(256) void k34_U(const float* __restrict__ ws,
                                             const float2* __restrict__ xmn,
                                             float2* __restrict__ U) {
    __shared__ float2 xh2s[1800];
    __shared__ float  S2s[1800];
    int bc = blockIdx.x, tid = threadIdx.x;

    for (int i = tid; i < 1800; i += 256) S2s[i] = ws[OFF_S2 + i];

    float2 acc[8];
#pragma unroll
    for (int l = 0; l < 8; ++l) acc[l] = make_float2(0.f, 0.f);
    if (tid < 225) {
        const float2* xp = xmn + (size_t)bc * 7200;
        const float4* dw = (const float4*)(ws + OFF_D2F);
        for (int j = 0; j < 32; ++j) {
            float2 xv = xp[j * 225 + tid];
            float4 dA = dw[(j * 225 + tid) * 2];
            float4 dB = dw[(j * 225 + tid) * 2 + 1];
            acc[0].x += dA.x * xv.x; acc[0].y += dA.x * xv.y;
            acc[1].x += dA.y * xv.x; acc[1].y += dA.y * xv.y;
            acc[2].x += dA.z * xv.x; acc[2].y += dA.z * xv.y;
            acc[3].x += dA.w * xv.x; acc[3].y += dA.w * xv.y;
            acc[4].x += dB.x * xv.x; acc[4].y += dB.x * xv.y;
            acc[5].x += dB.y * xv.x; acc[5].y += dB.y * xv.y;
            acc[6].x += dB.z * xv.x; acc[6].y += dB.z * xv.y;
            acc[7].x += dB.w * xv.x; acc[7].y += dB.w * xv.y;
        }
#pragma unroll
        for (int l = 0; l < 8; ++l) xh2s[l * 225 + tid] = acc[l];
    }
    __syncthreads();

    for (int idx = tid; idx < 1800; idx += 256) {
        int l = idx / 225;
        int rem = idx - l * 225;
        int n = rem / 15, k = rem - n * 15;
        float2 a = make_float2(0.f, 0.f);
        for (int m = 0; m < 15; ++m) {
            float s = S2s[(l * 15 + m) * 15 + n];
            float2 v = xh2s[l * 225 + m * 15 + k];
            a.x += s * v.x;
            a.y += s * v.y;
        }
        U[(size_t)bc * 1800 + idx] = a;
    }
}

// ---------- K5: DETERMINISTIC partials, block per (b,c): part[b][f][c] ----------
__global__ __launch_bounds__(256) void k5_part(const float* __restrict__ w2r,
                                               const float* __restrict__ w2i,
                                               const float2* __restrict__ U,
                                               float* __restrict__ part) {
    __shared__ float2 Us[1800];
    int b = blockIdx.x >> 5, c = blockIdx.x & 31;
    int tid = threadIdx.x;
    for (int i = tid; i < 1800; i += 256)
        Us[i] = U[(size_t)(b * 32 + c) * 1800 + i];
    __syncthreads();
    int f = tid >> 2, sub = tid & 3;
    float acc = 0.f;
    for (int idx = sub; idx < 1800; idx += 4) {
        int l = idx / 225;
        int nk = idx - l * 225;
        int n = nk / 15, k = nk - n * 15;
        if (iabs_(n - 7) > l || iabs_(k - 7) > l) continue;
        int wi = ((c * 64 + f) * 8 + l) * 225 + nk;
        float2 u = Us[idx];
        acc += u.x * w2r[wi] + u.y * w2i[wi];
    }
    acc += __shfl_down(acc, 2);
    acc += __shfl_down(acc, 1);
    if (sub == 0) part[(b * 64 + f) * 32 + c] = acc;
}

// ---------------- K6: c-sum + relu -> conv1d + relu + BN + fc ----------------
__global__ __launch_bounds__(640) void k6_head(const float* __restrict__ part,
                                               const float* __restrict__ w3,
                                               const float* __restrict__ b3,
                                               const float* __restrict__ gamma,
                                               const float* __restrict__ beta,
                                               const float* __restrict__ fcw,
                                               const float* __restrict__ fcb,
                                               float* __restrict__ out) {
    __shared__ float fL[1024];
    __shared__ float w3L[80];
    __shared__ float b3L[10];
    __shared__ float r3[9120];
    __shared__ float scaleL[10], shiftL[10];
    int tid = threadIdx.x;
    for (int i = tid; i < 1024; i += 640) {     // feat[b][f] = relu(sum_c part)
        const float* pp = part + i * 32;
        float s = 0.f;
#pragma unroll
        for (int c = 0; c < 32; ++c) s += pp[c];    // fixed order: deterministic
        fL[i] = fmaxf(s, 0.f);
    }
    if (tid < 80) w3L[tid] = w3[tid];
    if (tid >= 80 && tid < 90) b3L[tid - 80] = b3[tid - 80];
    __syncthreads();
    for (int i = tid; i < 9120; i += 640) {
        int ch = i / 912;
        int r = i % 912;
        int b = r / 57, pos = r % 57;
        float acc = b3L[ch];
#pragma unroll
        for (int t = 0; t < 8; ++t) acc += fL[b * 64 + pos + t] * w3L[ch * 8 + t];
        r3[ch * 912 + r] = fmaxf(acc, 0.0f);
    }
    __syncthreads();
    int wave = tid >> 6, lane = tid & 63;
    if (wave < 10) {
        float s = 0.f, s2 = 0.f;
        for (int i = lane; i < 912; i += 64) {
            float v = r3[wave * 912 + i];
            s += v;
            s2 += v * v;
        }
        for (int off = 32; off > 0; off >>= 1) {
            s += __shfl_down(s, off);
            s2 += __shfl_down(s2, off);
        }
        if (lane == 0) {
            float mu = s / 912.0f;
            float var = s2 / 912.0f - mu * mu;
            float sc = gamma[wave] * rsqrtf(var + 1e-5f);
            scaleL[wave] = sc;
            shiftL[wave] = beta[wave] - mu * sc;
        }
    }
    __syncthreads();
    {
        int pair = tid >> 2, sub = tid & 3;
        int b = pair / 10, o = pair % 10;
        float acc = 0.f;
        for (int idx = sub; idx < 570; idx += 4) {
            int ch = idx / 57, pos = idx - ch * 57;
            acc += (r3[ch * 912 + b * 57 + pos] * scaleL[ch] + shiftL[ch])
                   * fcw[o * 570 + idx];
        }
        acc += __shfl_down(acc, 2);
        acc += __shfl_down(acc, 1);
        if (sub == 0) out[b * 10 + o] = acc + fcb[o];
    }
}

extern "C" void kernel_launch(void* const* d_in, const int* in_sizes, int n_in,
                              void* d_out, int out_size, void* d_ws, size_t ws_size,
                              hipStream_t stream) {
    const float* x   = (const float*)d_in[0];
    const float* w1r = (const float*)d_in[1];
    const float* w1i = (const float*)d_in[2];
    const float* w2r = (const float*)d_in[3];
    const float* w2i = (const float*)d_in[4];
    const float* c3w = (const float*)d_in[5];
    const float* c3b = (const float*)d_in[6];
    const float* bng = (const float*)d_in[7];
    const float* bnb = (const float*)d_in[8];
    const float* fcw = (const float*)d_in[9];
    const float* fcb = (const float*)d_in[10];
    float* ws = (float*)d_ws;
    float* out = (float*)d_out;

    hipLaunchKernelGGL(k0a_tables, dim3(1), dim3(256), 0, stream, ws);
    hipLaunchKernelGGL(k0_consts, dim3(2341), dim3(256), 0, stream, ws);
    hipLaunchKernelGGL(k1_xh, dim3(4, 16), dim3(256), 0, stream, x, ws,
                       (float2*)(ws + OFF_XH));
    hipLaunchKernelGGL(k2_planes, dim3(32, 32, 16), dim3(256), 0, stream, w1r, w1i, ws,
                       (float2*)(ws + OFF_XMN));
    hipLaunchKernelGGL(k34_U, dim3(512), dim3(256), 0, stream, ws,
                       (const float2*)(ws + OFF_XMN), (float2*)(ws + OFF_U));
    hipLaunchKernelGGL(k5_part, dim3(512), dim3(256), 0, stream, w2r, w2i,
                       (const float2*)(ws + OFF_U), ws + OFF_PART);
    hipLaunchKernelGGL(k6_head, dim3(1), dim3(640), 0, stream, ws + OFF_PART,
                       c3w, c3b, bng, bnb, fcw, fcb, out);
}

// Round 9
// 362.040 us; speedup vs baseline: 1.0554x; 1.0554x over previous
//
#include <hip/hip_runtime.h>
#include <math.h>

#ifndef M_PI
#define M_PI 3.14159265358979323846
#endif

// ---------------- workspace layout (float offsets) ----------------
// double tables (k0a): [0..353] doubles at float offset 0 (708 floats, pad 720)
#define OFF_TRIG 708              // float2 cs32[32] then cs64[64]  (192 floats)
#define OFF_D1F 900               // [16][64][31]                 31744
#define OFF_D1I 32644             // D1IT: [j=32][mh=31][l=16][nh=32]  507904
#define OFF_D2F 540548            // D2FT: [j=32][pq=225][l=8]    57600
#define OFF_S2  598148            // [8][15][15]                   1800
#define OFF_XH  599948            // float2 [16][16*31]           15872 floats
#define OFF_XMN 615820            // float2 [16][32][32][225]   7372800 floats
#define OFF_U   7988620           // float2 [16*32][8][225]     1843200 floats
#define OFF_PART 9831820          // [16][64][256] (c*8+l)       262144 floats

static __device__ __forceinline__ int iabs_(int v) { return v < 0 ? -v : v; }

static __device__ __forceinline__ double powi_d(double x, int e) {
    double r = 1.0;
    while (e) { if (e & 1) r *= x; x *= x; e >>= 1; }
    return r;
}

// ---------------- K0a: tiny table precompute (1 block) ----------------
__global__ __launch_bounds__(256) void k0a_tables(float* __restrict__ ws) {
    double* T = (double*)ws;
    int t = threadIdx.x;
    __shared__ double lg[64];
    if (t < 64) lg[t] = (t == 0) ? 0.0 : log((double)t);
    __syncthreads();
    if (t == 0) {
        double s = 0.0;
        for (int i = 0; i < 64; ++i) { s += lg[i]; T[i] = s; }   // LF[i]=log(i!)
    }
    if (t < 64) {
        double beta = M_PI * (2.0 * t + 1.0) / 128.0;
        double s = 0.0;
        for (int k = 0; k < 32; ++k) s += sin((2.0 * k + 1.0) * beta) / (2.0 * k + 1.0);
        T[64 + t] = 2.0 / 32.0 * sin(beta) * s;
        T[160 + t] = cos(0.5 * beta);
        T[224 + t] = sin(0.5 * beta);
    }
    if (t >= 64 && t < 96) {
        int j = t - 64;
        double beta = M_PI * (2.0 * j + 1.0) / 64.0;
        double s = 0.0;
        for (int k = 0; k < 16; ++k) s += sin((2.0 * k + 1.0) * beta) / (2.0 * k + 1.0);
        T[128 + j] = 2.0 / 16.0 * sin(beta) * s;
        T[288 + j] = cos(0.5 * beta);
        T[320 + j] = sin(0.5 * beta);
    }
    if (t == 96) {
        T[352] = cos(M_PI / 64.0);
        T[353] = sin(M_PI / 64.0);
    }
    float2* F = (float2*)(ws + OFF_TRIG);
    if (t < 32) {
        double a = 2.0 * M_PI * (double)t / 32.0;
        F[t] = make_float2((float)cos(a), (float)sin(a));
    }
    if (t >= 128 && t < 192) {
        int i = t - 128;
        double a = 2.0 * M_PI * (double)i / 64.0;
        F[32 + i] = make_float2((float)cos(a), (float)sin(a));
    }
}

// ---------------- K0: build Wigner constant tables ----------------
__device__ double wig_fast(int l, int m, int n, double cb, double sb, const double* LF) {
    int kmin = max(0, m - n), kmax = min(l + m, l - n);
    if (kmax < kmin) return 0.0;
    double lc = 0.5 * (LF[l + m] + LF[l - m] + LF[l + n] + LF[l - n])
              - LF[kmin] - LF[l + m - kmin] - LF[l - n - kmin] - LF[n - m + kmin];
    double t = exp(lc) * powi_d(cb, 2 * l + m - n - 2 * kmin)
                       * powi_d(sb, n - m + 2 * kmin);
    if (kmin & 1) t = -t;
    double ratio = (sb * sb) / (cb * cb);
    double s = t;
    for (int k = kmin; k < kmax; ++k) {
        t *= -(((double)(l + m - k) * (double)(l - n - k)) /
               ((double)(k + 1) * (double)(n - m + k + 1))) * ratio;
        s += t;
    }
    return s;
}

__global__ __launch_bounds__(256) void k0_consts(float* __restrict__ ws) {
    const double* T = (const double*)ws;
    __shared__ double LF[64];
    int tid = threadIdx.x;
    if (tid < 64) LF[tid] = T[tid];
    __syncthreads();
    int gid = blockIdx.x * 256 + tid;
    if (gid >= 599048) return;

    if (gid < 31744) {                       // D1F [l][j][mh]
        int mh = gid % 31, j = (gid / 31) % 64, l = gid / (31 * 64);
        int m = mh - 15;
        double v = 0.0;
        if (iabs_(m) <= l)
            v = T[64 + j] * wig_fast(l, m, 0, T[160 + j], T[224 + j], LF);
        ws[OFF_D1F + gid] = (float)v;
    } else if (gid < 539648) {               // D1IT [j][mh][l][nh32]
        int r = gid - 31744;
        int nh = r & 31;
        int l  = (r >> 5) & 15;
        int mh = (r >> 9) % 31;
        int j  = r / (512 * 31);
        int m = mh - 15, n = nh - 15;
        double v = 0.0;
        if (nh < 31 && iabs_(m) <= l && iabs_(n) <= l)
            v = (2.0 * l + 1.0) * wig_fast(l, m, n, T[288 + j], T[320 + j], LF);
        ws[OFF_D1I + r] = (float)v;
    } else if (gid < 597248) {               // D2FT [j][pq][l]
        int r = gid - 539648;
        int l = r & 7;
        int pq = (r >> 3) % 225;
        int j = r / 1800;
        int mh = pq / 15, nh = pq % 15;
        int m = mh - 7, n = nh - 7;
        double v = 0.0;
        if (iabs_(m) <= l && iabs_(n) <= l)
            v = T[128 + j] * wig_fast(l, m, n, T[288 + j], T[320 + j], LF);
        ws[OFF_D2F + r] = (float)v;
    } else {                                 // S2 = D2I[:,0,:,:]
        int r = gid - 597248;
        int nh = r % 15, mh = (r / 15) % 15, l = r / 225;
        int m = mh - 7, n = nh - 7;
        double v = 0.0;
        if (iabs_(m) <= l && iabs_(n) <= l)
            v = (2.0 * l + 1.0) * wig_fast(l, m, n, T[352], T[353], LF);
        ws[OFF_S2 + r] = (float)v;
    }
}

// ---------------- K1: x -> xm -> xh ----------------
__global__ __launch_bounds__(256) void k1_xh(const float* __restrict__ x,
                                             const float* __restrict__ ws,
                                             float2* __restrict__ xh) {
    __shared__ float  xs[64 * 64];
    __shared__ float2 xm[64 * 8];
    __shared__ float2 cs64[64];
    int c = blockIdx.x, b = blockIdx.y, tid = threadIdx.x;
    int mh0 = c * 8;
    int cnt = min(8, 31 - mh0);
    for (int i = tid; i < 4096; i += 256) xs[i] = x[b * 4096 + i];
    if (tid < 64) cs64[tid] = ((const float2*)(ws + OFF_TRIG))[32 + tid];
    __syncthreads();
    for (int i = tid; i < 512; i += 256) {
        int j = i >> 3, mi = i & 7;
        if (mi < cnt) {
            int mu = mh0 + mi - 15;
            float re = 0.f, im = 0.f;
            for (int t = 0; t < 64; ++t) {
                float2 w = cs64[(mu * t) & 63];
                float xv = xs[j * 64 + t];
                re += xv * w.x;
                im -= xv * w.y;
            }
            xm[i] = make_float2(re, im);
        }
    }
    __syncthreads();
    const float* D1F = ws + OFF_D1F;
    if (tid < 128) {
        int l = tid >> 3, mi = tid & 7;
        if (mi < cnt) {
            int mh = mh0 + mi;
            float re = 0.f, im = 0.f;
            for (int j = 0; j < 64; ++j) {
                float d = D1F[(l * 64 + j) * 31 + mh];
                float2 v = xm[j * 8 + mi];
                re += d * v.x;
                im += d * v.y;
            }
            xh[b * 496 + l * 31 + mh] = make_float2(re, im);
        }
    }
}

// ------- K2: per-(b,f,j) plane; Hermitian-half iDFT2 + relu + fwd DFT2 -------
__global__ __launch_bounds__(256) void k2_planes(const float* __restrict__ w1r,
                                                 const float* __restrict__ w1i,
                                                 const float* __restrict__ ws,
                                                 float2* __restrict__ xmn) {
    __shared__ char ar[16896];
    __shared__ float2 cs[32];
    float2* As  = (float2*)ar;              // 496 f2 @0           (f1 phase)
    float2* Wc  = (float2*)(ar + 4096);     // 16x32 f2 @4096      (f1 phase)
    float2* f1  = (float2*)(ar + 8448);     // 31 rows stride34 f2 (dies after fH)
    float2* fH  = (float2*)ar;              // 16 rows stride34 f2 @0 [0,4352)
    float2* tls = (float2*)(ar + 4608);     // 17 rows stride33 f2 [4608,9096)
    float*  ssb = (float*)(ar + 9216);      // 32x33 f [9216,13440)
    float2* gg  = (float2*)ar;              // 32x15 f2 @0

    int j = blockIdx.x, f = blockIdx.y, b = blockIdx.z;
    int tid = threadIdx.x;
    const float2* xh = (const float2*)(ws + OFF_XH);

    if (tid < 32) cs[tid] = ((const float2*)(ws + OFF_TRIG))[tid];
    for (int i = tid; i < 496; i += 256) As[i] = xh[b * 496 + i];
    for (int i = tid; i < 512; i += 256) {
        int l = i >> 5, nh = i & 31;
        float mask = (nh < 31 && iabs_(nh - 15) <= l) ? 1.0f : 0.0f;
        int src = f * 496 + l * 31 + min(nh, 30);
        Wc[i] = make_float2(w1r[src] * mask, -w1i[src] * mask);
    }
    __syncthreads();
    // ---- f1[m, nh0..nh0+3] = sum_l D1IT[j,m,l,nh] * A[l,m] * W[l,nh] ----
    {
        int mrow = tid >> 3;
        int nh0 = (tid & 7) * 4;
        if (mrow < 31) {
            int l0 = iabs_(mrow - 15);
            float2 a0 = {0,0}, a1 = {0,0}, a2 = {0,0}, a3 = {0,0};
            const float* Dbase = ws + OFF_D1I + ((j * 31 + mrow) * 16) * 32 + nh0;
            for (int l = l0; l < 16; ++l) {
                float2 a = As[l * 31 + mrow];
                float4 w01 = *(const float4*)(Wc + l * 32 + nh0);
                float4 w23 = *(const float4*)(Wc + l * 32 + nh0 + 2);
                float4 d = *(const float4*)(Dbase + l * 32);
                float t;
                t = a.x*w01.x - a.y*w01.y; a0.x += d.x*t;
                t = a.x*w01.y + a.y*w01.x; a0.y += d.x*t;
                t = a.x*w01.z - a.y*w01.w; a1.x += d.y*t;
                t = a.x*w01.w + a.y*w01.z; a1.y += d.y*t;
                t = a.x*w23.x - a.y*w23.y; a2.x += d.z*t;
                t = a.x*w23.y + a.y*w23.x; a2.y += d.z*t;
                t = a.x*w23.z - a.y*w23.w; a3.x += d.w*t;
                t = a.x*w23.w + a.y*w23.z; a3.y += d.w*t;
            }
            float2* fr = f1 + mrow * 34 + nh0;
            fr[0] = a0; fr[1] = a1; fr[2] = a2; fr[3] = a3;
        }
    }
    __syncthreads();
    // ---- fH[mm,nh] = 0.5*(f1[mm+15,nh] + conj(f1[15-mm,30-nh])), mm=0..15 ----
    for (int i = tid; i < 512; i += 256) {
        int mm = i >> 5, nh = i & 31;
        float2 v = make_float2(0.f, 0.f);
        if (nh < 31) {
            float2 a = f1[(mm + 15) * 34 + nh];
            float2 bb = f1[(15 - mm) * 34 + (30 - nh)];
            v = make_float2(0.5f * (a.x + bb.x), 0.5f * (a.y - bb.y));
        }
        fH[mm * 34 + nh] = v;
    }
    __syncthreads();
    // ---- t[mm,v] = sum_n fH[mm,n] e^{+i n v th}, v = v0+8k (i^{nk} signs) ----
    if (tid < 128) {
        int mm = tid >> 3, v0 = tid & 7;
        const float2* frow = fH + mm * 34;
        float2 a0 = {0,0}, a1 = {0,0}, a2 = {0,0}, a3 = {0,0};
        for (int nb = 0; nb < 32; nb += 4) {
            float4 q01 = *(const float4*)(frow + nb);
            float4 q23 = *(const float4*)(frow + nb + 2);
            { // n mod 4 = 1
                float2 w = cs[((nb - 15) * v0) & 31];
                float px = q01.x*w.x - q01.y*w.y, py = q01.x*w.y + q01.y*w.x;
                a0.x += px; a0.y += py;  a1.x -= py; a1.y += px;
                a2.x -= px; a2.y -= py;  a3.x += py; a3.y -= px;
            }
            { // n mod 4 = 2
                float2 w = cs[((nb - 14) * v0) & 31];
                float px = q01.z*w.x - q01.w*w.y, py = q01.z*w.y + q01.w*w.x;
                a0.x += px; a0.y += py;  a1.x -= px; a1.y -= py;
                a2.x += px; a2.y += py;  a3.x -= px; a3.y -= py;
            }
            { // n mod 4 = 3
                float2 w = cs[((nb - 13) * v0) & 31];
                float px = q23.x*w.x - q23.y*w.y, py = q23.x*w.y + q23.y*w.x;
                a0.x += px; a0.y += py;  a1.x += py; a1.y -= px;
                a2.x -= px; a2.y -= py;  a3.x -= py; a3.y += px;
            }
            { // n mod 4 = 0
                float2 w = cs[((nb - 12) * v0) & 31];
                float px = q23.z*w.x - q23.w*w.y, py = q23.z*w.y + q23.w*w.x;
                a0.x += px; a0.y += py;  a1.x += px; a1.y += py;
                a2.x += px; a2.y += py;  a3.x += px; a3.y += py;
            }
        }
        float2* trow = tls + mm * 33;
        trow[v0] = a0; trow[v0 + 8] = a1; trow[v0 + 16] = a2; trow[v0 + 24] = a3;
    } else if (tid < 161) {
        tls[16 * 33 + (tid - 128)] = make_float2(0.f, 0.f);
    }
    __syncthreads();
    // ---- ss[u,v] = relu( t0.re + 2 sum_{m=1..15} Re(t[m,v] e^{imu th}) ) ----
    {
        int v = tid & 31, u0 = tid >> 5;
        float s0 = 0, s1 = 0, s2 = 0, s3 = 0;
        for (int mb = 0; mb < 4; ++mb) {
            int r1 = mb * 4 + 1;
            {
                float2 tv = tls[r1 * 33 + v];       float2 w = cs[(r1 * u0) & 31];
                float qx = tv.x*w.x - tv.y*w.y, qy = tv.x*w.y + tv.y*w.x;
                s0 += qx; s1 -= qy; s2 -= qx; s3 += qy;
            }
            {
                float2 tv = tls[(r1 + 1) * 33 + v]; float2 w = cs[((r1 + 1) * u0) & 31];
                float qx = tv.x*w.x - tv.y*w.y;
                s0 += qx; s1 -= qx; s2 += qx; s3 -= qx;
            }
            {
                float2 tv = tls[(r1 + 2) * 33 + v]; float2 w = cs[((r1 + 2) * u0) & 31];
                float qx = tv.x*w.x - tv.y*w.y, qy = tv.x*w.y + tv.y*w.x;
                s0 += qx; s1 += qy; s2 -= qx; s3 -= qy;
            }
            {
                float2 tv = tls[(r1 + 3) * 33 + v]; float2 w = cs[((r1 + 3) * u0) & 31];
                float qx = tv.x*w.x - tv.y*w.y;
                s0 += qx; s1 += qx; s2 += qx; s3 += qx;
            }
        }
        float t0x = tls[v].x;
        ssb[u0 * 33 + v]        = fmaxf(t0x + 2.f * s0, 0.f);
        ssb[(u0 + 8) * 33 + v]  = fmaxf(t0x + 2.f * s1, 0.f);
        ssb[(u0 + 16) * 33 + v] = fmaxf(t0x + 2.f * s2, 0.f);
        ssb[(u0 + 24) * 33 + v] = fmaxf(t0x + 2.f * s3, 0.f);
    }
    __syncthreads();
    // ---- gg[u,q'] = sum_v ss[u,v] e^{-i q' v th}, radix-4 over v ----
    {
        int u = tid >> 3, q = tid & 7;
        int qm = q & 3;
        float r1 = (qm == 0) ? 1.f : (qm == 2 ? -1.f : 0.f);
        float r2 = (qm & 1) ? -1.f : 1.f;
        float i1 = (qm == 1) ? -1.f : (qm == 3 ? 1.f : 0.f);
        float gx = 0.f, gy = 0.f;
        const float* srow = ssb + u * 33;
        for (int vb = 0; vb < 8; ++vb) {
            float s0 = srow[vb], s1 = srow[vb + 8], s2 = srow[vb + 16], s3 = srow[vb + 24];
            float zre = s0 + r1 * s1 + r2 * s2 + r1 * s3;
            float zim = i1 * (s1 - s3);
            float2 w = cs[(q * vb) & 31];
            gx += zre * w.x + zim * w.y;
            gy += zim * w.x - zre * w.y;
        }
        gg[u * 15 + 7 + q] = make_float2(gx, gy);
        if (q) gg[u * 15 + 7 - q] = make_float2(gx, -gy);
    }
    __syncthreads();
    // ---- h[p',q'] = sum_u gg[u,q'] e^{-i p' u th}, radix-4 over u ----
    if (tid < 113) {
        int ph, qh;
        if (tid < 105) { ph = 8 + tid / 15; qh = tid % 15; }
        else           { ph = 7; qh = 7 + (tid - 105); }
        int p = ph - 7;
        int pm = p & 3;
        float hx = 0.f, hy = 0.f;
        if ((pm & 1) == 0) {                  // even p
            float e = (pm == 0) ? 1.f : -1.f;
            for (int u0 = 0; u0 < 8; ++u0) {
                float2 g0 = gg[u0 * 15 + qh],        g1 = gg[(u0 + 8) * 15 + qh];
                float2 g2 = gg[(u0 + 16) * 15 + qh], g3 = gg[(u0 + 24) * 15 + qh];
                float zre = (g0.x + g2.x) + e * (g1.x + g3.x);
                float zim = (g0.y + g2.y) + e * (g1.y + g3.y);
                float2 w = cs[(-(p * u0)) & 31];
                hx += zre * w.x - zim * w.y;
                hy += zre * w.y + zim * w.x;
            }
        } else {                              // odd p
            float s = (pm == 1) ? 1.f : -1.f;
            for (int u0 = 0; u0 < 8; ++u0) {
                float2 g0 = gg[u0 * 15 + qh],        g1 = gg[(u0 + 8) * 15 + qh];
                float2 g2 = gg[(u0 + 16) * 15 + qh], g3 = gg[(u0 + 24) * 15 + qh];
                float dx = g1.x - g3.x, dy = g1.y - g3.y;
                float zre = (g0.x - g2.x) + s * dy;
                float zim = (g0.y - g2.y) - s * dx;
                float2 w = cs[(-(p * u0)) & 31];
                hx += zre * w.x - zim * w.y;
                hy += zre * w.y + zim * w.x;
            }
        }
        float2* outp = xmn + ((size_t)((b * 32 + f) * 32 + j)) * 225;
        outp[ph * 15 + qh] = make_float2(hx, hy);
        if (ph > 7 || qh > 7)
            outp[(14 - ph) * 15 + (14 - qh)] = make_float2(hx, -hy);
    }
}

// ---------- K34: fused xh2 + U, block per (b,c) ----------
__global__ __launch_bounds__(256) void k34_U(const float* __restrict__ ws,
                                             const float2* __restrict__ xmn,
                                             float2* __restrict__ U) {
    __shared__ float2 xh2s[1800];
    __shared__ float  S2s[1800];
    int bc = blockIdx.x, tid = threadIdx.x;

    for (int i = tid; i < 1800; i += 256) S2s[i] = ws[OFF_S2 + i];

    float2 acc[8];
#pragma unroll
    for (int l = 0; l < 8; ++l) acc[l] = make_float2(0.f, 0.f);
    if (tid < 225) {
        const float2* xp = xmn + (size_t)bc * 7200;
        const float4* dw = (const float4*)(ws + OFF_D2F);
        for (int j = 0; j < 32; ++j) {
            float2 xv = xp[j * 225 + tid];
            float4 dA = dw[(j * 225 + tid) * 2];
            float4 dB = dw[(j * 225 + tid) * 2 + 1];
            acc[0].x += dA.x * xv.x; acc[0].y += dA.x * xv.y;
            acc[1].x += dA.y * xv.x; acc[1].y += dA.y * xv.y;
            acc[2].x += dA.z * xv.x; acc[2].y += dA.z * xv.y;
            acc[3].x += dA.w * xv.x; acc[3].y += dA.w * xv.y;
            acc[4].x += dB.x * xv.x; acc[4].y += dB.x * xv.y;
            acc[5].x += dB.y * xv.x; acc[5].y += dB.y * xv.y;
            acc[6].x += dB.z * xv.x; acc[6].y += dB.z * xv.y;
            acc[7].x += dB.w * xv.x; acc[7].y += dB.w * xv.y;
        }
#pragma unroll
        for (int l = 0; l < 8; ++l) xh2s[l * 225 + tid] = acc[l];
    }
    __syncthreads();

    for (int idx = tid; idx < 1800; idx += 256) {
        int l = idx / 225;
        int rem = idx - l * 225;
        int n = rem / 15, k = rem - n * 15;
        float2 a = make_float2(0.f, 0.f);
        for (int m = 0; m < 15; ++m) {
            float s = S2s[(l * 15 + m) * 15 + n];
            float2 v = xh2s[l * 225 + m * 15 + k];
            a.x += s * v.x;
            a.y += s * v.y;
        }
        U[(size_t)bc * 1800 + idx] = a;
    }
}

// ---------- K5: block per (c,l), fc loop; U & w2 read ONCE; deterministic partial writes ----------
__global__ __launch_bounds__(256) void k5_part(const float* __restrict__ w2r,
                                               const float* __restrict__ w2i,
                                               const float2* __restrict__ U,
                                               float* __restrict__ part) {
    __shared__ char arr[57600];
    float2* Us  = (float2*)arr;             // 16b x 225 f2
    float2* Wsh = (float2*)(arr + 28800);   // 16f x 225 f2
    int c = blockIdx.x >> 3, l = blockIdx.x & 7;
    int tid = threadIdx.x;

    for (int i = tid; i < 3600; i += 256) {
        int b = i / 225, t = i - b * 225;
        Us[i] = U[(size_t)(b * 32 + c) * 1800 + l * 225 + t];
    }
    int cl = c * 8 + l;
    for (int fc = 0; fc < 4; ++fc) {
        __syncthreads();
        for (int i = tid; i < 3600; i += 256) {
            int f = fc * 16 + i / 225;
            int t = i % 225;
            int n = t / 15, k = t - n * 15;
            bool valid = (iabs_(n - 7) <= l) && (iabs_(k - 7) <= l);
            int wi = ((c * 64 + f) * 8 + l) * 225 + t;
            Wsh[i] = valid ? make_float2(w2r[wi], w2i[wi]) : make_float2(0.f, 0.f);
        }
        __syncthreads();
        int b = tid >> 4, fl = tid & 15;
        float accv = 0.f;
        const float2* up = Us + b * 225;
        const float2* wp = Wsh + fl * 225;
        for (int t = 0; t < 225; ++t)                 // fixed order: deterministic
            accv += up[t].x * wp[t].x + up[t].y * wp[t].y;
        part[(b * 64 + fc * 16 + fl) * 256 + cl] = accv;   // unique slot, no atomics
    }
}

// ---------------- K6: partial-sum + relu -> conv1d + relu + BN + fc ----------------
__global__ __launch_bounds__(640) void k6_head(const float* __restrict__ part,
                                               const float* __restrict__ w3,
                                               const float* __restrict__ b3,
                                               const float* __restrict__ gamma,
                                               const float* __restrict__ beta,
                                               const float* __restrict__ fcw,
                                               const float* __restrict__ fcb,
                                               float* __restrict__ out) {
    __shared__ float fL[1024];
    __shared__ float w3L[80];
    __shared__ float b3L[10];
    __shared__ float r3[9120];
    __shared__ float scaleL[10], shiftL[10];
    int tid = threadIdx.x;
    for (int i = tid; i < 1024; i += 640) {     // feat[b][f] = relu(sum_{cl} part)
        const float4* pp = (const float4*)(part + i * 256);
        float s = 0.f;
        for (int c4 = 0; c4 < 64; ++c4) {       // fixed order: deterministic
            float4 p = pp[c4];
            s += p.x; s += p.y; s += p.z; s += p.w;
        }
        fL[i] = fmaxf(s, 0.f);
    }
    if (tid < 80) w3L[tid] = w3[tid];
    if (tid >= 80 && tid < 90) b3L[tid - 80] = b3[tid - 80];
    __syncthreads();
    for (int i = tid; i < 9120; i += 640) {
        int ch = i / 912;
        int r = i % 912;
        int b = r / 57, pos = r % 57;
        float acc = b3L[ch];
#pragma unroll
        for (int t = 0; t < 8; ++t) acc += fL[b * 64 + pos + t] * w3L[ch * 8 + t];
        r3[ch * 912 + r] = fmaxf(acc, 0.0f);
    }
    __syncthreads();
    int wave = tid >> 6, lane = tid & 63;
    if (wave < 10) {
        float s = 0.f, s2 = 0.f;
        for (int i = lane; i < 912; i += 64) {
            float v = r3[wave * 912 + i];
            s += v;
            s2 += v * v;
        }
        for (int off = 32; off > 0; off >>= 1) {
            s += __shfl_down(s, off);
            s2 += __shfl_down(s2, off);
        }
        if (lane == 0) {
            float mu = s / 912.0f;
            float var = s2 / 912.0f - mu * mu;
            float sc = gamma[wave] * rsqrtf(var + 1e-5f);
            scaleL[wave] = sc;
            shiftL[wave] = beta[wave] - mu * sc;
        }
    }
    __syncthreads();
    {
        int pair = tid >> 2, sub = tid & 3;
        int b = pair / 10, o = pair % 10;
        float acc = 0.f;
        for (int idx = sub; idx < 570; idx += 4) {
            int ch = idx / 57, pos = idx - ch * 57;
            acc += (r3[ch * 912 + b * 57 + pos] * scaleL[ch] + shiftL[ch])
                   * fcw[o * 570 + idx];
        }
        acc += __shfl_down(acc, 2);
        acc += __shfl_down(acc, 1);
        if (sub == 0) out[b * 10 + o] = acc + fcb[o];
    }
}

extern "C" void kernel_launch(void* const* d_in, const int* in_sizes, int n_in,
                              void* d_out, int out_size, void* d_ws, size_t ws_size,
                              hipStream_t stream) {
    const float* x   = (const float*)d_in[0];
    const float* w1r = (const float*)d_in[1];
    const float* w1i = (const float*)d_in[2];
    const float* w2r = (const float*)d_in[3];
    const float* w2i = (const float*)d_in[4];
    const float* c3w = (const float*)d_in[5];
    const float* c3b = (const float*)d_in[6];
    const float* bng = (const float*)d_in[7];
    const float* bnb = (const float*)d_in[8];
    const float* fcw = (const float*)d_in[9];
    const float* fcb = (const float*)d_in[10];
    float* ws = (float*)d_ws;
    float* out = (float*)d_out;

    hipLaunchKernelGGL(k0a_tables, dim3(1), dim3(256), 0, stream, ws);
    hipLaunchKernelGGL(k0_consts, dim3(2341), dim3(256), 0, stream, ws);
    hipLaunchKernelGGL(k1_xh, dim3(4, 16), dim3(256), 0, stream, x, ws,
                       (float2*)(ws + OFF_XH));
    hipLaunchKernelGGL(k2_planes, dim3(32, 32, 16), dim3(256), 0, stream, w1r, w1i, ws,
                       (float2*)(ws + OFF_XMN));
    hipLaunchKernelGGL(k34_U, dim3(512), dim3(256), 0, stream, ws,
                       (const float2*)(ws + OFF_XMN), (float2*)(ws + OFF_U));
    hipLaunchKernelGGL(k5_part, dim3(256), dim3(256), 0, stream, w2r, w2i,
                       (const float2*)(ws + OFF_U), ws + OFF_PART);
    hipLaunchKernelGGL(k6_head, dim3(1), dim3(640), 0, stream, ws + OFF_PART,
                       c3w, c3b, bng, bnb, fcw, fcb, out);
}

// Round 10
// 326.161 us; speedup vs baseline: 1.1715x; 1.1100x over previous
//
#include <hip/hip_runtime.h>
#include <math.h>

#ifndef M_PI
#define M_PI 3.14159265358979323846
#endif

// ---------------- workspace layout (float offsets) ----------------
#define OFF_TRIG 708              // float2 cs32[32] then cs64[64]  (192 floats)
#define OFF_D1F 900               // [16][64][31]                 31744
#define OFF_D1I 32644             // D1IT: [j=32][mh=31][l=16][nh=32]  507904
#define OFF_D2F 540548            // D2FT: [j=32][pq=225][l=8]    57600
#define OFF_S2  598148            // [8][15][15]                   1800
#define OFF_XH  599948            // float2 [16][16*31]           15872 floats
#define OFF_XMN 615820            // float2 [16][32][32][225]   7372800 floats
#define OFF_U   7988620           // float2 [16*32][8][225]     1843200 floats
#define OFF_PART 9831820          // [cl=256][bf=1024]           262144 floats

static __device__ __forceinline__ int iabs_(int v) { return v < 0 ? -v : v; }

static __device__ __forceinline__ double powi_d(double x, int e) {
    double r = 1.0;
    while (e) { if (e & 1) r *= x; x *= x; e >>= 1; }
    return r;
}

// ---------------- K0: per-block tables + Wigner constants (fused) ----------------
__device__ double wig_fast(int l, int m, int n, double cb, double sb, const double* LF) {
    int kmin = max(0, m - n), kmax = min(l + m, l - n);
    if (kmax < kmin) return 0.0;
    double lc = 0.5 * (LF[l + m] + LF[l - m] + LF[l + n] + LF[l - n])
              - LF[kmin] - LF[l + m - kmin] - LF[l - n - kmin] - LF[n - m + kmin];
    double t = exp(lc) * powi_d(cb, 2 * l + m - n - 2 * kmin)
                       * powi_d(sb, n - m + 2 * kmin);
    if (kmin & 1) t = -t;
    double ratio = (sb * sb) / (cb * cb);
    double s = t;
    for (int k = kmin; k < kmax; ++k) {
        t *= -(((double)(l + m - k) * (double)(l - n - k)) /
               ((double)(k + 1) * (double)(n - m + k + 1))) * ratio;
        s += t;
    }
    return s;
}

__global__ __launch_bounds__(256) void k0_consts(float* __restrict__ ws) {
    // Td: LF[64] | w0[64]@64 | w1q[32]@128 | cb0@160 | sb0@224 | cb1@288 | sb1@320 | cb2s@352 sb2s@353
    __shared__ double Td[354];
    int tid = threadIdx.x;
    if (tid < 64) {
        double s = (tid == 0) ? 0.0 : log((double)tid);
        for (int off = 1; off < 64; off <<= 1) {
            double up = __shfl_up(s, off, 64);
            if (tid >= off) s += up;
        }
        Td[tid] = s;                               // log(tid!)
    } else if (tid < 128) {
        int j = tid - 64;
        double beta = M_PI * (2.0 * j + 1.0) / 128.0;
        double sb = sin(beta), c2 = cos(2.0 * beta);
        double cur = sb, prev = -sb, sum = 0.0;
        for (int k = 0; k < 32; ++k) {
            sum += cur / (2.0 * k + 1.0);
            double nxt = 2.0 * c2 * cur - prev;
            prev = cur; cur = nxt;
        }
        Td[64 + j] = (2.0 / 32.0) * sb * sum;
        Td[160 + j] = cos(0.5 * beta);
        Td[224 + j] = sin(0.5 * beta);
    } else if (tid < 160) {
        int j = tid - 128;
        double beta = M_PI * (2.0 * j + 1.0) / 64.0;
        double sb = sin(beta), c2 = cos(2.0 * beta);
        double cur = sb, prev = -sb, sum = 0.0;
        for (int k = 0; k < 16; ++k) {
            sum += cur / (2.0 * k + 1.0);
            double nxt = 2.0 * c2 * cur - prev;
            prev = cur; cur = nxt;
        }
        Td[128 + j] = (2.0 / 16.0) * sb * sum;
        Td[288 + j] = cos(0.5 * beta);
        Td[320 + j] = sin(0.5 * beta);
    } else if (tid == 160) {
        Td[352] = cos(M_PI / 64.0);
        Td[353] = sin(M_PI / 64.0);
    }
    __syncthreads();

    if (blockIdx.x == 0) {                     // float twiddle tables
        float2* F = (float2*)(ws + OFF_TRIG);
        if (tid < 32) {
            double a = 2.0 * M_PI * (double)tid / 32.0;
            F[tid] = make_float2((float)cos(a), (float)sin(a));
        }
        if (tid >= 128 && tid < 192) {
            int i = tid - 128;
            double a = 2.0 * M_PI * (double)i / 64.0;
            F[32 + i] = make_float2((float)cos(a), (float)sin(a));
        }
    }

    int gid = blockIdx.x * 256 + tid;
    if (gid >= 599048) return;
    const double* T = Td;

    if (gid < 31744) {                       // D1F [l][j][mh]
        int mh = gid % 31, j = (gid / 31) % 64, l = gid / (31 * 64);
        int m = mh - 15;
        double v = 0.0;
        if (iabs_(m) <= l)
            v = T[64 + j] * wig_fast(l, m, 0, T[160 + j], T[224 + j], T);
        ws[OFF_D1F + gid] = (float)v;
    } else if (gid < 539648) {               // D1IT [j][mh][l][nh32]
        int r = gid - 31744;
        int nh = r & 31;
        int l  = (r >> 5) & 15;
        int mh = (r >> 9) % 31;
        int j  = r / (512 * 31);
        int m = mh - 15, n = nh - 15;
        double v = 0.0;
        if (nh < 31 && iabs_(m) <= l && iabs_(n) <= l)
            v = (2.0 * l + 1.0) * wig_fast(l, m, n, T[288 + j], T[320 + j], T);
        ws[OFF_D1I + r] = (float)v;
    } else if (gid < 597248) {               // D2FT [j][pq][l]
        int r = gid - 539648;
        int l = r & 7;
        int pq = (r >> 3) % 225;
        int j = r / 1800;
        int mh = pq / 15, nh = pq % 15;
        int m = mh - 7, n = nh - 7;
        double v = 0.0;
        if (iabs_(m) <= l && iabs_(n) <= l)
            v = T[128 + j] * wig_fast(l, m, n, T[288 + j], T[320 + j], T);
        ws[OFF_D2F + r] = (float)v;
    } else {                                 // S2 = D2I[:,0,:,:]
        int r = gid - 597248;
        int nh = r % 15, mh = (r / 15) % 15, l = r / 225;
        int m = mh - 7, n = nh - 7;
        double v = 0.0;
        if (iabs_(m) <= l && iabs_(n) <= l)
            v = (2.0 * l + 1.0) * wig_fast(l, m, n, T[352], T[353], T);
        ws[OFF_S2 + r] = (float)v;
    }
}

// ---------------- K1: x -> xm -> xh ----------------
__global__ __launch_bounds__(256) void k1_xh(const float* __restrict__ x,
                                             const float* __restrict__ ws,
                                             float2* __restrict__ xh) {
    __shared__ float  xs[64 * 64];
    __shared__ float2 xm[64 * 8];
    __shared__ float2 cs64[64];
    int c = blockIdx.x, b = blockIdx.y, tid = threadIdx.x;
    int mh0 = c * 8;
    int cnt = min(8, 31 - mh0);
    for (int i = tid; i < 4096; i += 256) xs[i] = x[b * 4096 + i];
    if (tid < 64) cs64[tid] = ((const float2*)(ws + OFF_TRIG))[32 + tid];
    __syncthreads();
    for (int i = tid; i < 512; i += 256) {
        int j = i >> 3, mi = i & 7;
        if (mi < cnt) {
            int mu = mh0 + mi - 15;
            float re = 0.f, im = 0.f;
            for (int t = 0; t < 64; ++t) {
                float2 w = cs64[(mu * t) & 63];
                float xv = xs[j * 64 + t];
                re += xv * w.x;
                im -= xv * w.y;
            }
            xm[i] = make_float2(re, im);
        }
    }
    __syncthreads();
    const float* D1F = ws + OFF_D1F;
    if (tid < 128) {
        int l = tid >> 3, mi = tid & 7;
        if (mi < cnt) {
            int mh = mh0 + mi;
            float re = 0.f, im = 0.f;
            for (int j = 0; j < 64; ++j) {
                float d = D1F[(l * 64 + j) * 31 + mh];
                float2 v = xm[j * 8 + mi];
                re += d * v.x;
                im += d * v.y;
            }
            xh[b * 496 + l * 31 + mh] = make_float2(re, im);
        }
    }
}

// ------- K2: per-(b,f,j) plane; Hermitian-half iDFT2 + relu + fwd DFT2 -------
__global__ __launch_bounds__(256) void k2_planes(const float* __restrict__ w1r,
                                                 const float* __restrict__ w1i,
                                                 const float* __restrict__ ws,
                                                 float2* __restrict__ xmn) {
    __shared__ char ar[16896];
    __shared__ float2 cs[32];
    float2* As  = (float2*)ar;              // 496 f2 @0           (f1 phase)
    float2* Wc  = (float2*)(ar + 4096);     // 16x32 f2 @4096      (f1 phase)
    float2* f1  = (float2*)(ar + 8448);     // 31 rows stride34 f2 (dies after fH)
    float2* fH  = (float2*)ar;              // 16 rows stride34 f2 @0 [0,4352)
    float2* tls = (float2*)(ar + 4608);     // 17 rows stride33 f2 [4608,9096)
    float*  ssb = (float*)(ar + 9216);      // 32x33 f [9216,13440)
    float2* gg  = (float2*)ar;              // 32x15 f2 @0

    int j = blockIdx.x, f = blockIdx.y, b = blockIdx.z;
    int tid = threadIdx.x;
    const float2* xh = (const float2*)(ws + OFF_XH);

    if (tid < 32) cs[tid] = ((const float2*)(ws + OFF_TRIG))[tid];
    for (int i = tid; i < 496; i += 256) As[i] = xh[b * 496 + i];
    for (int i = tid; i < 512; i += 256) {
        int l = i >> 5, nh = i & 31;
        float mask = (nh < 31 && iabs_(nh - 15) <= l) ? 1.0f : 0.0f;
        int src = f * 496 + l * 31 + min(nh, 30);
        Wc[i] = make_float2(w1r[src] * mask, -w1i[src] * mask);
    }
    __syncthreads();
    // ---- f1[m, nh0..nh0+3] = sum_l D1IT[j,m,l,nh] * A[l,m] * W[l,nh] ----
    {
        int mrow = tid >> 3;
        int nh0 = (tid & 7) * 4;
        if (mrow < 31) {
            int l0 = iabs_(mrow - 15);
            float2 a0 = {0,0}, a1 = {0,0}, a2 = {0,0}, a3 = {0,0};
            const float* Dbase = ws + OFF_D1I + ((j * 31 + mrow) * 16) * 32 + nh0;
            for (int l = l0; l < 16; ++l) {
                float2 a = As[l * 31 + mrow];
                float4 w01 = *(const float4*)(Wc + l * 32 + nh0);
                float4 w23 = *(const float4*)(Wc + l * 32 + nh0 + 2);
                float4 d = *(const float4*)(Dbase + l * 32);
                float t;
                t = a.x*w01.x - a.y*w01.y; a0.x += d.x*t;
                t = a.x*w01.y + a.y*w01.x; a0.y += d.x*t;
                t = a.x*w01.z - a.y*w01.w; a1.x += d.y*t;
                t = a.x*w01.w + a.y*w01.z; a1.y += d.y*t;
                t = a.x*w23.x - a.y*w23.y; a2.x += d.z*t;
                t = a.x*w23.y + a.y*w23.x; a2.y += d.z*t;
                t = a.x*w23.z - a.y*w23.w; a3.x += d.w*t;
                t = a.x*w23.w + a.y*w23.z; a3.y += d.w*t;
            }
            float2* fr = f1 + mrow * 34 + nh0;
            fr[0] = a0; fr[1] = a1; fr[2] = a2; fr[3] = a3;
        }
    }
    __syncthreads();
    // ---- fH[mm,nh] = 0.5*(f1[mm+15,nh] + conj(f1[15-mm,30-nh])), mm=0..15 ----
    for (int i = tid; i < 512; i += 256) {
        int mm = i >> 5, nh = i & 31;
        float2 v = make_float2(0.f, 0.f);
        if (nh < 31) {
            float2 a = f1[(mm + 15) * 34 + nh];
            float2 bb = f1[(15 - mm) * 34 + (30 - nh)];
            v = make_float2(0.5f * (a.x + bb.x), 0.5f * (a.y - bb.y));
        }
        fH[mm * 34 + nh] = v;
    }
    __syncthreads();
    // ---- t[mm,v] = sum_n fH[mm,n] e^{+i n v th}, v = v0+8k (i^{nk} signs) ----
    if (tid < 128) {
        int mm = tid >> 3, v0 = tid & 7;
        const float2* frow = fH + mm * 34;
        float2 a0 = {0,0}, a1 = {0,0}, a2 = {0,0}, a3 = {0,0};
        for (int nb = 0; nb < 32; nb += 4) {
            float4 q01 = *(const float4*)(frow + nb);
            float4 q23 = *(const float4*)(frow + nb + 2);
            { // n mod 4 = 1
                float2 w = cs[((nb - 15) * v0) & 31];
                float px = q01.x*w.x - q01.y*w.y, py = q01.x*w.y + q01.y*w.x;
                a0.x += px; a0.y += py;  a1.x -= py; a1.y += px;
                a2.x -= px; a2.y -= py;  a3.x += py; a3.y -= px;
            }
            { // n mod 4 = 2
                float2 w = cs[((nb - 14) * v0) & 31];
                float px = q01.z*w.x - q01.w*w.y, py = q01.z*w.y + q01.w*w.x;
                a0.x += px; a0.y += py;  a1.x -= px; a1.y -= py;
                a2.x += px; a2.y += py;  a3.x -= px; a3.y -= py;
            }
            { // n mod 4 = 3
                float2 w = cs[((nb - 13) * v0) & 31];
                float px = q23.x*w.x - q23.y*w.y, py = q23.x*w.y + q23.y*w.x;
                a0.x += px; a0.y += py;  a1.x += py; a1.y -= px;
                a2.x -= px; a2.y -= py;  a3.x -= py; a3.y += px;
            }
            { // n mod 4 = 0
                float2 w = cs[((nb - 12) * v0) & 31];
                float px = q23.z*w.x - q23.w*w.y, py = q23.z*w.y + q23.w*w.x;
                a0.x += px; a0.y += py;  a1.x += px; a1.y += py;
                a2.x += px; a2.y += py;  a3.x += px; a3.y += py;
            }
        }
        float2* trow = tls + mm * 33;
        trow[v0] = a0; trow[v0 + 8] = a1; trow[v0 + 16] = a2; trow[v0 + 24] = a3;
    } else if (tid < 161) {
        tls[16 * 33 + (tid - 128)] = make_float2(0.f, 0.f);
    }
    __syncthreads();
    // ---- ss[u,v] = relu( t0.re + 2 sum_{m=1..15} Re(t[m,v] e^{imu th}) ) ----
    {
        int v = tid & 31, u0 = tid >> 5;
        float s0 = 0, s1 = 0, s2 = 0, s3 = 0;
        for (int mb = 0; mb < 4; ++mb) {
            int r1 = mb * 4 + 1;
            {
                float2 tv = tls[r1 * 33 + v];       float2 w = cs[(r1 * u0) & 31];
                float qx = tv.x*w.x - tv.y*w.y, qy = tv.x*w.y + tv.y*w.x;
                s0 += qx; s1 -= qy; s2 -= qx; s3 += qy;
            }
            {
                float2 tv = tls[(r1 + 1) * 33 + v]; float2 w = cs[((r1 + 1) * u0) & 31];
                float qx = tv.x*w.x - tv.y*w.y;
                s0 += qx; s1 -= qx; s2 += qx; s3 -= qx;
            }
            {
                float2 tv = tls[(r1 + 2) * 33 + v]; float2 w = cs[((r1 + 2) * u0) & 31];
                float qx = tv.x*w.x - tv.y*w.y, qy = tv.x*w.y + tv.y*w.x;
                s0 += qx; s1 += qy; s2 -= qx; s3 -= qy;
            }
            {
                float2 tv = tls[(r1 + 3) * 33 + v]; float2 w = cs[((r1 + 3) * u0) & 31];
                float qx = tv.x*w.x - tv.y*w.y;
                s0 += qx; s1 += qx; s2 += qx; s3 += qx;
            }
        }
        float t0x = tls[v].x;
        ssb[u0 * 33 + v]        = fmaxf(t0x + 2.f * s0, 0.f);
        ssb[(u0 + 8) * 33 + v]  = fmaxf(t0x + 2.f * s1, 0.f);
        ssb[(u0 + 16) * 33 + v] = fmaxf(t0x + 2.f * s2, 0.f);
        ssb[(u0 + 24) * 33 + v] = fmaxf(t0x + 2.f * s3, 0.f);
    }
    __syncthreads();
    // ---- gg[u,q'] = sum_v ss[u,v] e^{-i q' v th}, radix-4 over v ----
    {
        int u = tid >> 3, q = tid & 7;
        int qm = q & 3;
        float r1 = (qm == 0) ? 1.f : (qm == 2 ? -1.f : 0.f);
        float r2 = (qm & 1) ? -1.f : 1.f;
        float i1 = (qm == 1) ? -1.f : (qm == 3 ? 1.f : 0.f);
        float gx = 0.f, gy = 0.f;
        const float* srow = ssb + u * 33;
        for (int vb = 0; vb < 8; ++vb) {
            float s0 = srow[vb], s1 = srow[vb + 8], s2 = srow[vb + 16], s3 = srow[vb + 24];
            float zre = s0 + r1 * s1 + r2 * s2 + r1 * s3;
            float zim = i1 * (s1 - s3);
            float2 w = cs[(q * vb) & 31];
            gx += zre * w.x + zim * w.y;
            gy += zim * w.x - zre * w.y;
        }
        gg[u * 15 + 7 + q] = make_float2(gx, gy);
        if (q) gg[u * 15 + 7 - q] = make_float2(gx, -gy);
    }
    __syncthreads();
    // ---- h[p',q'] = sum_u gg[u,q'] e^{-i p' u th}, radix-4 over u ----
    if (tid < 113) {
        int ph, qh;
        if (tid < 105) { ph = 8 + tid / 15; qh = tid % 15; }
        else           { ph = 7; qh = 7 + (tid - 105); }
        int p = ph - 7;
        int pm = p & 3;
        float hx = 0.f, hy = 0.f;
        if ((pm & 1) == 0) {                  // even p
            float e = (pm == 0) ? 1.f : -1.f;
            for (int u0 = 0; u0 < 8; ++u0) {
                float2 g0 = gg[u0 * 15 + qh],        g1 = gg[(u0 + 8) * 15 + qh];
                float2 g2 = gg[(u0 + 16) * 15 + qh], g3 = gg[(u0 + 24) * 15 + qh];
                float zre = (g0.x + g2.x) + e * (g1.x + g3.x);
                float zim = (g0.y + g2.y) + e * (g1.y + g3.y);
                float2 w = cs[(-(p * u0)) & 31];
                hx += zre * w.x - zim * w.y;
                hy += zre * w.y + zim * w.x;
            }
        } else {                              // odd p
            float s = (pm == 1) ? 1.f : -1.f;
            for (int u0 = 0; u0 < 8; ++u0) {
                float2 g0 = gg[u0 * 15 + qh],        g1 = gg[(u0 + 8) * 15 + qh];
                float2 g2 = gg[(u0 + 16) * 15 + qh], g3 = gg[(u0 + 24) * 15 + qh];
                float dx = g1.x - g3.x, dy = g1.y - g3.y;
                float zre = (g0.x - g2.x) + s * dy;
                float zim = (g0.y - g2.y) - s * dx;
                float2 w = cs[(-(p * u0)) & 31];
                hx += zre * w.x - zim * w.y;
                hy += zre * w.y + zim * w.x;
            }
        }
        float2* outp = xmn + ((size_t)((b * 32 + f) * 32 + j)) * 225;
        outp[ph * 15 + qh] = make_float2(hx, hy);
        if (ph > 7 || qh > 7)
            outp[(14 - ph) * 15 + (14 - qh)] = make_float2(hx, -hy);
    }
}

// ---------- K34: fused xh2 + U, block per (b,c) ----------
__global__ __launch_bounds__(256) void k34_U(const float* __restrict__ ws,
                                             const float2* __restrict__ xmn,
                                             float2* __restrict__ U) {
    __shared__ float2 xh2s[1800];
    __shared__ float  S2s[1800];
    int bc = blockIdx.x, tid = threadIdx.x;

    for (int i = tid; i < 1800; i += 256) S2s[i] = ws[OFF_S2 + i];

    float2 acc[8];
#pragma unroll
    for (int l = 0; l < 8; ++l) acc[l] = make_float2(0.f, 0.f);
    if (tid < 225) {
        const float2* xp = xmn + (size_t)bc * 7200;
        const float4* dw = (const float4*)(ws + OFF_D2F);
        for (int j = 0; j < 32; ++j) {
            float2 xv = xp[j * 225 + tid];
            float4 dA = dw[(j * 225 + tid) * 2];
            float4 dB = dw[(j * 225 + tid) * 2 + 1];
            acc[0].x += dA.x * xv.x; acc[0].y += dA.x * xv.y;
            acc[1].x += dA.y * xv.x; acc[1].y += dA.y * xv.y;
            acc[2].x += dA.z * xv.x; acc[2].y += dA.z * xv.y;
            acc[3].x += dA.w * xv.x; acc[3].y += dA.w * xv.y;
            acc[4].x += dB.x * xv.x; acc[4].y += dB.x * xv.y;
            acc[5].x += dB.y * xv.x; acc[5].y += dB.y * xv.y;
            acc[6].x += dB.z * xv.x; acc[6].y += dB.z * xv.y;
            acc[7].x += dB.w * xv.x; acc[7].y += dB.w * xv.y;
        }
#pragma unroll
        for (int l = 0; l < 8; ++l) xh2s[l * 225 + tid] = acc[l];
    }
    __syncthreads();

    for (int idx = tid; idx < 1800; idx += 256) {
        int l = idx / 225;
        int rem = idx - l * 225;
        int n = rem / 15, k = rem - n * 15;
        float2 a = make_float2(0.f, 0.f);
        for (int m = 0; m < 15; ++m) {
            float s = S2s[(l * 15 + m) * 15 + n];
            float2 v = xh2s[l * 225 + m * 15 + k];
            a.x += s * v.x;
            a.y += s * v.y;
        }
        U[(size_t)bc * 1800 + idx] = a;
    }
}

// ---------- K5: 1024 blocks (c,l,fc), one task each; deterministic transposed partials ----------
__global__ __launch_bounds__(256) void k5_part(const float* __restrict__ w2r,
                                               const float* __restrict__ w2i,
                                               const float2* __restrict__ U,
                                               float* __restrict__ part) {
    __shared__ char arr[57600];
    float2* Us  = (float2*)arr;             // 16b x 225 f2
    float2* Wsh = (float2*)(arr + 28800);   // 16f x 225 f2
    int bx = blockIdx.x;
    int c = bx >> 5, l = (bx >> 2) & 7, fc = bx & 3;
    int tid = threadIdx.x;

    for (int i = tid; i < 3600; i += 256) {
        int b = i / 225, t = i - b * 225;
        Us[i] = U[(size_t)(b * 32 + c) * 1800 + l * 225 + t];
    }
    for (int i = tid; i < 3600; i += 256) {
        int f = fc * 16 + i / 225;
        int t = i % 225;
        int n = t / 15, k = t - n * 15;
        bool valid = (iabs_(n - 7) <= l) && (iabs_(k - 7) <= l);
        int wi = ((c * 64 + f) * 8 + l) * 225 + t;
        Wsh[i] = valid ? make_float2(w2r[wi], w2i[wi]) : make_float2(0.f, 0.f);
    }
    __syncthreads();
    int b = tid >> 4, fl = tid & 15;
    float accv = 0.f;
    const float2* up = Us + b * 225;
    const float2* wp = Wsh + fl * 225;
    for (int t = 0; t < 225; ++t)                 // fixed order: deterministic
        accv += up[t].x * wp[t].x + up[t].y * wp[t].y;
    int cl = c * 8 + l;
    int bf = b * 64 + fc * 16 + fl;
    part[cl * 1024 + bf] = accv;                  // unique slot, no atomics
}

// ---------------- K6: coalesced partial-sum + relu -> conv1d + relu + BN + fc ----------------
__global__ __launch_bounds__(640) void k6_head(const float* __restrict__ part,
                                               const float* __restrict__ w3,
                                               const float* __restrict__ b3,
                                               const float* __restrict__ gamma,
                                               const float* __restrict__ beta,
                                               const float* __restrict__ fcw,
                                               const float* __restrict__ fcb,
                                               float* __restrict__ out) {
    __shared__ float fL[1024];
    __shared__ float w3L[80];
    __shared__ float b3L[10];
    __shared__ float r3[9120];
    __shared__ float scaleL[10], shiftL[10];
    int tid = threadIdx.x;
    if (tid < 512) {                 // feat[bf] = relu(sum_cl part[cl][bf]), coalesced
        float s0 = 0.f, s1 = 0.f;
        for (int cl = 0; cl < 256; ++cl) {       // fixed order: deterministic
            const float* pr = part + cl * 1024;
            s0 += pr[tid];
            s1 += pr[tid + 512];
        }
        fL[tid]       = fmaxf(s0, 0.f);
        fL[tid + 512] = fmaxf(s1, 0.f);
    }
    if (tid >= 512 && tid < 592) w3L[tid - 512] = w3[tid - 512];
    if (tid >= 592 && tid < 602) b3L[tid - 592] = b3[tid - 592];
    __syncthreads();
    for (int i = tid; i < 9120; i += 640) {
        int ch = i / 912;
        int r = i % 912;
        int b = r / 57, pos = r % 57;
        float acc = b3L[ch];
#pragma unroll
        for (int t = 0; t < 8; ++t) acc += fL[b * 64 + pos + t] * w3L[ch * 8 + t];
        r3[ch * 912 + r] = fmaxf(acc, 0.0f);
    }
    __syncthreads();
    int wave = tid >> 6, lane = tid & 63;
    if (wave < 10) {
        float s = 0.f, s2 = 0.f;
        for (int i = lane; i < 912; i += 64) {
            float v = r3[wave * 912 + i];
            s += v;
            s2 += v * v;
        }
        for (int off = 32; off > 0; off >>= 1) {
            s += __shfl_down(s, off);
            s2 += __shfl_down(s2, off);
        }
        if (lane == 0) {
            float mu = s / 912.0f;
            float var = s2 / 912.0f - mu * mu;
            float sc = gamma[wave] * rsqrtf(var + 1e-5f);
            scaleL[wave] = sc;
            shiftL[wave] = beta[wave] - mu * sc;
        }
    }
    __syncthreads();
    {
        int pair = tid >> 2, sub = tid & 3;
        int b = pair / 10, o = pair % 10;
        float acc = 0.f;
        for (int idx = sub; idx < 570; idx += 4) {
            int ch = idx / 57, pos = idx - ch * 57;
            acc += (r3[ch * 912 + b * 57 + pos] * scaleL[ch] + shiftL[ch])
                   * fcw[o * 570 + idx];
        }
        acc += __shfl_down(acc, 2);
        acc += __shfl_down(acc, 1);
        if (sub == 0) out[b * 10 + o] = acc + fcb[o];
    }
}

extern "C" void kernel_launch(void* const* d_in, const int* in_sizes, int n_in,
                              void* d_out, int out_size, void* d_ws, size_t ws_size,
                              hipStream_t stream) {
    const float* x   = (const float*)d_in[0];
    const float* w1r = (const float*)d_in[1];
    const float* w1i = (const float*)d_in[2];
    const float* w2r = (const float*)d_in[3];
    const float* w2i = (const float*)d_in[4];
    const float* c3w = (const float*)d_in[5];
    const float* c3b = (const float*)d_in[6];
    const float* bng = (const float*)d_in[7];
    const float* bnb = (const float*)d_in[8];
    const float* fcw = (const float*)d_in[9];
    const float* fcb = (const float*)d_in[10];
    float* ws = (float*)d_ws;
    float* out = (float*)d_out;

    hipLaunchKernelGGL(k0_consts, dim3(2341), dim3(256), 0, stream, ws);
    hipLaunchKernelGGL(k1_xh, dim3(4, 16), dim3(256), 0, stream, x, ws,
                       (float2*)(ws + OFF_XH));
    hipLaunchKernelGGL(k2_planes, dim3(32, 32, 16), dim3(256), 0, stream, w1r, w1i, ws,
                       (float2*)(ws + OFF_XMN));
    hipLaunchKernelGGL(k34_U, dim3(512), dim3(256), 0, stream, ws,
                       (const float2*)(ws + OFF_XMN), (float2*)(ws + OFF_U));
    hipLaunchKernelGGL(k5_part, dim3(1024), dim3(256), 0, stream, w2r, w2i,
                       (const float2*)(ws + OFF_U), ws + OFF_PART);
    hipLaunchKernelGGL(k6_head, dim3(1), dim3(640), 0, stream, ws + OFF_PART,
                       c3w, c3b, bng, bnb, fcw, fcb, out);
}